// Round 15
// baseline (813.151 us; speedup 1.0000x reference)
//
#include <hip/hip_runtime.h>
#include <hip/hip_bf16.h>
#include <math.h>

#define NN 10000
#define EE 320000
#define DIM 256
#define NROWS 10016   // NN padded to 32
#define SCANB 40      // ceil(NN/256)

typedef __attribute__((ext_vector_type(8))) _Float16 f16x8;
typedef __attribute__((ext_vector_type(4))) _Float16 f16x4;
typedef __attribute__((ext_vector_type(2))) _Float16 f16x2;
typedef __attribute__((ext_vector_type(4))) float f32x4;

#if defined(__has_builtin)
#if __has_builtin(__builtin_amdgcn_fdot2)
#define FDOT2(a, b, c) __builtin_amdgcn_fdot2(a, b, c, false)
#endif
#endif
#ifndef FDOT2
#define FDOT2(a, b, c) fmaf((float)a[0], (float)b[0], fmaf((float)a[1], (float)b[1], c))
#endif

__device__ __forceinline__ float bf2f(unsigned short u) {
  union { unsigned int ui; float f; } cv;
  cv.ui = ((unsigned int)u) << 16;
  return cv.f;
}

__device__ __forceinline__ float ldf(const void* p, int idx, int isf) {
  return isf ? ((const float*)p)[idx] : bf2f(((const unsigned short*)p)[idx]);
}

// block 0 wave 0: detect {f32 vs bf16} and {int64 vs int32}; block 1: zero bsum;
// all blocks: zero counts
__global__ __launch_bounds__(256) void k_detect_zero(const unsigned int* __restrict__ xw,
                                                     const int* __restrict__ ei,
                                                     int* __restrict__ flags,
                                                     int* __restrict__ counts,
                                                     int* __restrict__ bsum) {
  int i = blockIdx.x * 256 + (int)threadIdx.x;
  if (i < NN) counts[i] = 0;
  if (blockIdx.x == 1 && threadIdx.x < 64) bsum[threadIdx.x] = 0;
  if (blockIdx.x == 0 && threadIdx.x < 64) {
    int lane = threadIdx.x;
    int wild = 0;
    for (int t = 0; t < 16; ++t) {
      unsigned int w = xw[t * 64 + lane];
      unsigned int lo = w & 0xffffu;
      float f = bf2f((unsigned short)lo);
      float af = fabsf(f);
      if (lo != 0u && (af > 1e4f || af < 1e-30f)) wild++;
    }
    #pragma unroll
    for (int m = 1; m < 64; m <<= 1) wild += __shfl_xor(wild, m);
    int zeros = 0;
    for (int t = 0; t < 2; ++t) {
      if (ei[(t * 64 + lane) * 2 + 1] == 0) zeros++;
    }
    #pragma unroll
    for (int m = 1; m < 64; m <<= 1) zeros += __shfl_xor(zeros, m);
    if (lane == 0) {
      flags[0] = (wild > 100) ? 1 : 0;   // 1: floats f32
      flags[1] = (zeros > 100) ? 1 : 0;  // 1: indices int64
    }
  }
}

// degree count; also accumulate 256-node block sums for the scan
__global__ void k_count(const int* __restrict__ ei, int* __restrict__ counts,
                        int* __restrict__ bsum, const int* __restrict__ flags) {
  int i64 = flags[1];
  int i = blockIdx.x * blockDim.x + threadIdx.x;
  if (i < EE) {
    int d = i64 ? ei[2 * (EE + i)] : ei[EE + i];
    atomicAdd(&counts[d], 1);
    atomicAdd(&bsum[d >> 8], 1);
  }
}

// single-kernel scan: per-block inclusive scan + base from bsum -> offsets, cursor
__global__ __launch_bounds__(256) void k_scan_all(const int* __restrict__ counts,
                                                  const int* __restrict__ bsum,
                                                  int* __restrict__ offsets,
                                                  int* __restrict__ cursor) {
  __shared__ int s[256];
  __shared__ int sbase;
  int t = (int)threadIdx.x, b = (int)blockIdx.x;
  int i = b * 256 + t;
  int v = (i < NN) ? counts[i] : 0;
  s[t] = v;
  if (t < 64) {
    int x = (t < SCANB && t < b) ? bsum[t] : 0;
    #pragma unroll
    for (int msk = 1; msk < 64; msk <<= 1) x += __shfl_xor(x, msk);
    if (t == 0) sbase = x;
  }
  __syncthreads();
  for (int off = 1; off < 256; off <<= 1) {
    int x = (t >= off) ? s[t - off] : 0;
    __syncthreads();
    s[t] += x;
    __syncthreads();
  }
  if (i < NN) {
    int o = sbase + s[t] - v;
    offsets[i] = o;
    cursor[i] = o;
  }
  if (i == 0) offsets[NN] = EE;
}

__global__ void k_fill_sort(const int* __restrict__ ei, const void* __restrict__ ew,
                            int* __restrict__ cursor, int2* __restrict__ eS,
                            const int* __restrict__ flags) {
  int isf = flags[0];
  int i64 = flags[1];
  int i = blockIdx.x * blockDim.x + threadIdx.x;
  if (i < EE) {
    int s, d;
    if (i64) { s = ei[2 * i]; d = ei[2 * (EE + i)]; }
    else     { s = ei[i];     d = ei[EE + i]; }
    float wv = isf ? ((const float*)ew)[i] : bf2f(((const unsigned short*)ew)[i]);
    int p = atomicAdd(&cursor[d], 1);
    eS[p] = make_int2(s, __float_as_int(wv));
  }
}

struct PackArgs {
  const void* W[8];    // 256x256 weight matrices
  const void* B8[8];   // 256 biases
  const void* WeWb[4]; // we1(256), wb1(768), we2(256), wb2(768)
  const void* x;
};

// fused param pack. blocks 0..127: W transpose via 64x64 LDS tiles (coalesced both ways).
// blocks 128..143: biases + We/Wb. blocks 144+: x -> Ah fp16 (zero-pad rows >= NN).
__global__ __launch_bounds__(256) void k_pack(PackArgs pa, _Float16* __restrict__ Bh,
                                              float* __restrict__ bvec,
                                              float* __restrict__ WeWbF,
                                              _Float16* __restrict__ Ah,
                                              const int* __restrict__ flags) {
  __shared__ _Float16 lds[64][66];
  int isf = flags[0];
  int bid = (int)blockIdx.x, tid = (int)threadIdx.x;
  if (bid < 128) {
    int m = bid >> 4, t = bid & 15, tr = t >> 2, tc = t & 3;
    const void* Wm = pa.W[m];
    #pragma unroll
    for (int rep = 0; rep < 16; ++rep) {
      int idx = rep * 256 + tid;
      int r = idx >> 6, c = idx & 63;
      lds[r][c] = (_Float16)ldf(Wm, (tr * 64 + r) * 256 + tc * 64 + c, isf);
    }
    __syncthreads();
    _Float16* out = Bh + (size_t)m * 65536;
    #pragma unroll
    for (int rep = 0; rep < 16; ++rep) {
      int idx = rep * 256 + tid;
      int r = idx >> 6, c = idx & 63;
      out[(tc * 64 + r) * 256 + tr * 64 + c] = lds[c][r];
    }
    return;
  }
  int b2 = bid - 128;
  if (b2 < 16) {
    int i = b2 * 256 + tid;  // 0..4095
    if (i < 2048) {
      bvec[i] = ldf(pa.B8[i >> 8], i & 255, isf);
    } else {
      i -= 2048;
      int which, k;
      if (i < 256)       { which = 0; k = i; }
      else if (i < 1024) { which = 1; k = i - 256; }
      else if (i < 1280) { which = 2; k = i - 1024; }
      else               { which = 3; k = i - 1280; }
      WeWbF[i] = ldf(pa.WeWb[which], k, isf);
    }
    return;
  }
  int i = (b2 - 16) * 256 + tid;
  if (i < NROWS * 64) {
    f16x4 h;
    if (i >= NN * 64) {
      h = (f16x4)(_Float16)0.f;
    } else {
      float v[4];
      if (isf) {
        float4 t = reinterpret_cast<const float4*>(pa.x)[i];
        v[0] = t.x; v[1] = t.y; v[2] = t.z; v[3] = t.w;
      } else {
        ushort4 t = reinterpret_cast<const ushort4*>(pa.x)[i];
        v[0] = bf2f(t.x); v[1] = bf2f(t.y); v[2] = bf2f(t.z); v[3] = bf2f(t.w);
      }
      #pragma unroll
      for (int j = 0; j < 4; ++j) h[j] = (_Float16)v[j];
    }
    reinterpret_cast<f16x4*>(Ah)[i] = h;
  }
}

// fp16 MFMA GEMM, 32-row x 256-col tiles, single pass for all matrices.
// blockIdx.y = matrix: 0=Q(fp16) 1=K(fp16) 2=V(fp16) 3=XR(f32)
__global__ __launch_bounds__(256, 4) void k_gemm_mfma(
    const _Float16* __restrict__ Ah, const _Float16* __restrict__ Bh,
    const float* __restrict__ bvec, _Float16* __restrict__ Qh,
    _Float16* __restrict__ KVh, float* __restrict__ XRf) {
  int tid = (int)threadIdx.x;
  int wave = tid >> 6, lane = tid & 63;
  int lr = lane & 15;
  int kg = (lane >> 4) << 3;
  int mat = blockIdx.y;
  int rowBase = blockIdx.x << 5;
  int colBase = (mat << 8) + (wave << 6);
  const _Float16* a0 = Ah + (size_t)(rowBase + lr) * 256 + kg;
  const _Float16* b0 = Bh + (size_t)(colBase + lr) * 256 + kg;
  f32x4 acc[2][4] = {};
  #pragma unroll
  for (int ks = 0; ks < 256; ks += 32) {
    f16x8 ah0 = *reinterpret_cast<const f16x8*>(a0 + ks);
    f16x8 ah1 = *reinterpret_cast<const f16x8*>(a0 + 16 * 256 + ks);
    f16x8 bh[4];
    #pragma unroll
    for (int cf = 0; cf < 4; ++cf)
      bh[cf] = *reinterpret_cast<const f16x8*>(b0 + cf * 16 * 256 + ks);
    #pragma unroll
    for (int cf = 0; cf < 4; ++cf) {
      acc[0][cf] = __builtin_amdgcn_mfma_f32_16x16x32_f16(ah0, bh[cf], acc[0][cf], 0, 0, 0);
      acc[1][cf] = __builtin_amdgcn_mfma_f32_16x16x32_f16(ah1, bh[cf], acc[1][cf], 0, 0, 0);
    }
  }
  int rj = (lane >> 4) << 2;
  int colLoc = (wave << 6);
  #pragma unroll
  for (int rf = 0; rf < 2; ++rf) {
    #pragma unroll
    for (int cf = 0; cf < 4; ++cf) {
      int col = colLoc + cf * 16 + lr;
      float bb = bvec[(mat << 8) + col];
      #pragma unroll
      for (int j = 0; j < 4; ++j) {
        int row = rowBase + rf * 16 + rj + j;
        if (row < NN) {
          float val = acc[rf][cf][j] + bb;
          if (mat == 0)      Qh[(size_t)row * DIM + col] = (_Float16)val;
          else if (mat == 3) XRf[(size_t)row * DIM + col] = val;
          else KVh[(size_t)row * 512 + ((mat == 2) ? 256 : 0) + col] = (_Float16)val;
        }
      }
    }
  }
}

// single-edge online-softmax step (qwe/sw form)
#define ATT_STEP(KK, VV, WW) do { \
    f16x2 kka = {KK[0], KK[1]}, kkb = {KK[2], KK[3]}; \
    float pt = FDOT2(kka, qha, FDOT2(kkb, qhb, 0.f)); \
    pt += __shfl_xor(pt, 1); \
    pt += __shfl_xor(pt, 2); \
    pt += __shfl_xor(pt, 4); \
    float alpha = fmaf(WW, qwe, pt) * 0.17677669529663687f; \
    float nm = fmaxf(m, alpha); \
    float sc = __expf(m - nm); \
    float pe = __expf(alpha - nm); \
    l = fmaf(l, sc, pe); \
    sw = fmaf(sw, sc, pe * WW); \
    a0 = fmaf(a0, sc, pe * (float)VV[0]); \
    a1 = fmaf(a1, sc, pe * (float)VV[1]); \
    a2 = fmaf(a2, sc, pe * (float)VV[2]); \
    a3 = fmaf(a3, sc, pe * (float)VV[3]); \
    m = nm; \
  } while (0)

// two edges per update: independent packed dots, one max3, one rescale
#define PAIR_STEP(K0, V0, W0, K1, V1, W1) do { \
    f16x2 k0a = {K0[0], K0[1]}, k0b = {K0[2], K0[3]}; \
    f16x2 k1a = {K1[0], K1[1]}, k1b = {K1[2], K1[3]}; \
    float pt0 = FDOT2(k0a, qha, FDOT2(k0b, qhb, 0.f)); \
    float pt1 = FDOT2(k1a, qha, FDOT2(k1b, qhb, 0.f)); \
    pt0 += __shfl_xor(pt0, 1); pt1 += __shfl_xor(pt1, 1); \
    pt0 += __shfl_xor(pt0, 2); pt1 += __shfl_xor(pt1, 2); \
    pt0 += __shfl_xor(pt0, 4); pt1 += __shfl_xor(pt1, 4); \
    float al0 = fmaf(W0, qwe, pt0) * 0.17677669529663687f; \
    float al1 = fmaf(W1, qwe, pt1) * 0.17677669529663687f; \
    float nm = fmaxf(fmaxf(m, al0), al1); \
    float sc = __expf(m - nm); \
    float p0 = __expf(al0 - nm); \
    float p1 = __expf(al1 - nm); \
    l = fmaf(l, sc, p0 + p1); \
    sw = fmaf(sw, sc, fmaf(p0, W0, p1 * W1)); \
    a0 = fmaf(a0, sc, fmaf(p0, (float)V0[0], p1 * (float)V1[0])); \
    a1 = fmaf(a1, sc, fmaf(p0, (float)V0[1], p1 * (float)V1[1])); \
    a2 = fmaf(a2, sc, fmaf(p0, (float)V0[2], p1 * (float)V1[2])); \
    a3 = fmaf(a3, sc, fmaf(p0, (float)V0[3], p1 * (float)V1[3])); \
    m = nm; \
  } while (0)

// one wave per node; pair-batched online softmax with algebraic We elimination.
__global__ __launch_bounds__(256) void k_attn(
    const _Float16* __restrict__ Qh, const _Float16* __restrict__ KVh,
    const float* __restrict__ XRf, const float* __restrict__ We,
    const float* __restrict__ Wb, const int2* __restrict__ eS,
    const int* __restrict__ offsets, _Float16* __restrict__ Ah,
    float* __restrict__ FinalOut) {
  int wid = (int)threadIdx.x >> 6, lane = (int)threadIdx.x & 63;
  int node = blockIdx.x * 4 + wid;
  if (node >= NN) return;
  int d0 = lane * 4;
  const f16x4 qh4 = *reinterpret_cast<const f16x4*>(&Qh[(size_t)node * DIM + d0]);
  const float4 x4 = *reinterpret_cast<const float4*>(&XRf[(size_t)node * DIM + d0]);
  const float4 we4 = *reinterpret_cast<const float4*>(&We[d0]);
  const float4 wo = *reinterpret_cast<const float4*>(&Wb[d0]);
  const float4 wx = *reinterpret_cast<const float4*>(&Wb[DIM + d0]);
  const float4 wd = *reinterpret_cast<const float4*>(&Wb[2 * DIM + d0]);
  f16x2 qha = {qh4[0], qh4[1]};
  f16x2 qhb = {qh4[2], qh4[3]};
  float qwe = (float)qh4[0] * we4.x + (float)qh4[1] * we4.y
            + (float)qh4[2] * we4.z + (float)qh4[3] * we4.w;
  qwe += __shfl_xor(qwe, 1);
  qwe += __shfl_xor(qwe, 2);
  qwe += __shfl_xor(qwe, 4);
  int beg = offsets[node], end = offsets[node + 1];
  beg = __builtin_amdgcn_readfirstlane(beg);
  end = __builtin_amdgcn_readfirstlane(end);
  float m = -INFINITY, l = 0.f, sw = 0.f, a0 = 0.f, a1 = 0.f, a2 = 0.f, a3 = 0.f;
  int p = beg;
  if ((end - beg) & 1) {
    int2 e = eS[p];
    float w0 = __int_as_float(e.y);
    const _Float16* r = KVh + (size_t)e.x * 512 + d0;
    f16x4 k0 = *reinterpret_cast<const f16x4*>(r);
    f16x4 v0 = *reinterpret_cast<const f16x4*>(r + 256);
    ATT_STEP(k0, v0, w0);
    ++p;
  }
  if (p < end) {  // even remaining count >= 2
    int2 eA0 = eS[p], eA1 = eS[p + 1];
    int pb = (p + 3 < end) ? (p + 2) : p;
    int2 eB0 = eS[pb], eB1 = eS[pb + 1];
    const _Float16* rA0 = KVh + (size_t)eA0.x * 512 + d0;
    const _Float16* rA1 = KVh + (size_t)eA1.x * 512 + d0;
    const _Float16* rB0 = KVh + (size_t)eB0.x * 512 + d0;
    const _Float16* rB1 = KVh + (size_t)eB1.x * 512 + d0;
    f16x4 kA0 = *reinterpret_cast<const f16x4*>(rA0), vA0 = *reinterpret_cast<const f16x4*>(rA0 + 256);
    f16x4 kA1 = *reinterpret_cast<const f16x4*>(rA1), vA1 = *reinterpret_cast<const f16x4*>(rA1 + 256);
    f16x4 kB0 = *reinterpret_cast<const f16x4*>(rB0), vB0 = *reinterpret_cast<const f16x4*>(rB0 + 256);
    f16x4 kB1 = *reinterpret_cast<const f16x4*>(rB1), vB1 = *reinterpret_cast<const f16x4*>(rB1 + 256);
    float wA0 = __int_as_float(eA0.y), wA1 = __int_as_float(eA1.y);
    float wB0 = __int_as_float(eB0.y), wB1 = __int_as_float(eB1.y);
    #pragma unroll 2
    for (; p + 2 < end; p += 2) {
      int pc = (p + 5 < end) ? (p + 4) : p;
      int2 eC0 = eS[pc], eC1 = eS[pc + 1];
      const _Float16* rC0 = KVh + (size_t)eC0.x * 512 + d0;
      const _Float16* rC1 = KVh + (size_t)eC1.x * 512 + d0;
      f16x4 kC0 = *reinterpret_cast<const f16x4*>(rC0), vC0 = *reinterpret_cast<const f16x4*>(rC0 + 256);
      f16x4 kC1 = *reinterpret_cast<const f16x4*>(rC1), vC1 = *reinterpret_cast<const f16x4*>(rC1 + 256);
      float wC0 = __int_as_float(eC0.y), wC1 = __int_as_float(eC1.y);
      PAIR_STEP(kA0, vA0, wA0, kA1, vA1, wA1);
      kA0 = kB0; vA0 = vB0; wA0 = wB0; kA1 = kB1; vA1 = vB1; wA1 = wB1;
      kB0 = kC0; vB0 = vC0; wB0 = wC0; kB1 = kC1; vB1 = vC1; wB1 = wC1;
    }
    PAIR_STEP(kA0, vA0, wA0, kA1, vA1, wA1);
  }
  float inv = 1.f / (l + 1e-16f);
  float o0 = fmaf(sw, we4.x, a0) * inv;
  float o1 = fmaf(sw, we4.y, a1) * inv;
  float o2 = fmaf(sw, we4.z, a2) * inv;
  float o3 = fmaf(sw, we4.w, a3) * inv;
  float part = o0 * wo.x + o1 * wo.y + o2 * wo.z + o3 * wo.w
             + x4.x * wx.x + x4.y * wx.y + x4.z * wx.z + x4.w * wx.w
             + (o0 - x4.x) * wd.x + (o1 - x4.y) * wd.y
             + (o2 - x4.z) * wd.z + (o3 - x4.w) * wd.w;
  #pragma unroll
  for (int msk = 1; msk < 64; msk <<= 1) part += __shfl_xor(part, msk);
  float beta = 1.f / (1.f + __expf(-part));
  float h0 = beta * x4.x + (1.f - beta) * o0;
  float h1 = beta * x4.y + (1.f - beta) * o1;
  float h2 = beta * x4.z + (1.f - beta) * o2;
  float h3 = beta * x4.w + (1.f - beta) * o3;
  if (FinalOut) {
    float4 h; h.x = h0; h.y = h1; h.z = h2; h.w = h3;
    *reinterpret_cast<float4*>(&FinalOut[(size_t)node * DIM + d0]) = h;
  } else {
    f16x4 hh;
    hh[0] = (_Float16)h0; hh[1] = (_Float16)h1;
    hh[2] = (_Float16)h2; hh[3] = (_Float16)h3;
    *reinterpret_cast<f16x4*>(&Ah[(size_t)node * DIM + d0]) = hh;
  }
}

static inline size_t align256(size_t v) { return (v + 255) & ~(size_t)255; }

extern "C" void kernel_launch(void* const* d_in, const int* in_sizes, int n_in,
                              void* d_out, int out_size, void* d_ws, size_t ws_size,
                              hipStream_t stream) {
  const void* x = d_in[0];
  const int* eidx = (const int*)d_in[1];
  const void* ew = d_in[2];

  char* w = (char*)d_ws;
  size_t pos = 0;
  int* flags = (int*)(w + pos); pos = align256(pos + 2 * sizeof(int));
  _Float16* Qh = (_Float16*)(w + pos); pos = align256(pos + (size_t)NROWS * DIM * 2);
  float* XRf = (float*)(w + pos); pos = align256(pos + (size_t)NROWS * DIM * 4);
  _Float16* KVh = (_Float16*)(w + pos); pos = align256(pos + (size_t)NROWS * 512 * 2);
  _Float16* Ah = (_Float16*)(w + pos); pos = align256(pos + (size_t)NROWS * DIM * 2);
  _Float16* Bh = (_Float16*)(w + pos); pos = align256(pos + (size_t)8 * 65536 * 2);
  float* bvec  = (float*)(w + pos); pos = align256(pos + 2048 * 4);
  float* WeWbF = (float*)(w + pos); pos = align256(pos + 2048 * 4);
  int2* eS   = (int2*)(w + pos);   pos = align256(pos + (size_t)EE * 8);
  int* counts  = (int*)(w + pos);  pos = align256(pos + (size_t)NN * 4);
  int* offsets = (int*)(w + pos);  pos = align256(pos + (size_t)(NN + 1) * 4);
  int* cursor  = (int*)(w + pos);  pos = align256(pos + (size_t)NN * 4);
  int* bsum    = (int*)(w + pos);  pos = align256(pos + 64 * 4);

  // params: d_in[3..22], order per group: Wq bq Wk bk Wv bv We Wskip bskip Wbeta
  PackArgs pa;
  pa.x = x;
  for (int g = 0; g < 2; ++g) {
    const void* const* pp = &d_in[3 + g * 10];
    pa.W[g * 4 + 0] = pp[0]; pa.W[g * 4 + 1] = pp[2];
    pa.W[g * 4 + 2] = pp[4]; pa.W[g * 4 + 3] = pp[7];
    pa.B8[g * 4 + 0] = pp[1]; pa.B8[g * 4 + 1] = pp[3];
    pa.B8[g * 4 + 2] = pp[5]; pa.B8[g * 4 + 3] = pp[8];
    pa.WeWb[g * 2 + 0] = pp[6];
    pa.WeWb[g * 2 + 1] = pp[9];
  }

  k_detect_zero<<<SCANB, 256, 0, stream>>>((const unsigned int*)x, eidx, flags, counts, bsum);
  k_pack<<<128 + 16 + (NROWS * 64 + 255) / 256, 256, 0, stream>>>(
      pa, Bh, bvec, WeWbF, Ah, flags);
  k_count<<<(EE + 255) / 256, 256, 0, stream>>>(eidx, counts, bsum, flags);
  k_scan_all<<<SCANB, 256, 0, stream>>>(counts, bsum, offsets, cursor);
  k_fill_sort<<<(EE + 255) / 256, 256, 0, stream>>>(eidx, ew, cursor, eS, flags);

  for (int layer = 0; layer < 3; ++layer) {
    int g = (layer == 0) ? 0 : 1;
    k_gemm_mfma<<<dim3(NROWS / 32, 4), 256, 0, stream>>>(
        Ah, Bh + (size_t)g * 4 * 65536, bvec + g * 1024, Qh, KVh, XRf);
    k_attn<<<(NN + 3) / 4, 256, 0, stream>>>(Qh, KVh, XRf,
        WeWbF + (g ? 1024 : 0), WeWbF + (g ? 1280 : 256),
        eS, offsets, Ah, (layer == 2) ? (float*)d_out : nullptr);
  }
}

// Round 16
// 291.068 us; speedup vs baseline: 2.7937x; 2.7937x over previous
//
#include <hip/hip_runtime.h>
#include <hip/hip_bf16.h>
#include <math.h>

#define NN 10000
#define EE 320000
#define DIM 256
#define NROWS 10016   // NN padded to 32
#define SCANB 40      // ceil(NN/256)

typedef __attribute__((ext_vector_type(8))) _Float16 f16x8;
typedef __attribute__((ext_vector_type(4))) _Float16 f16x4;
typedef __attribute__((ext_vector_type(2))) _Float16 f16x2;
typedef __attribute__((ext_vector_type(4))) float f32x4;

#if defined(__has_builtin)
#if __has_builtin(__builtin_amdgcn_fdot2)
#define FDOT2(a, b, c) __builtin_amdgcn_fdot2(a, b, c, false)
#endif
#endif
#ifndef FDOT2
#define FDOT2(a, b, c) fmaf((float)a[0], (float)b[0], fmaf((float)a[1], (float)b[1], c))
#endif

__device__ __forceinline__ float bf2f(unsigned short u) {
  union { unsigned int ui; float f; } cv;
  cv.ui = ((unsigned int)u) << 16;
  return cv.f;
}

__device__ __forceinline__ float ldf(const void* p, int idx, int isf) {
  return isf ? ((const float*)p)[idx] : bf2f(((const unsigned short*)p)[idx]);
}

// block 0 wave 0: detect {f32 vs bf16} and {int64 vs int32}; all blocks: zero counts
__global__ __launch_bounds__(256) void k_detect_zero(const unsigned int* __restrict__ xw,
                                                     const int* __restrict__ ei,
                                                     int* __restrict__ flags,
                                                     int* __restrict__ counts) {
  int i = blockIdx.x * 256 + (int)threadIdx.x;
  if (i < NN) counts[i] = 0;
  if (blockIdx.x == 0 && threadIdx.x < 64) {
    int lane = threadIdx.x;
    int wild = 0;
    for (int t = 0; t < 16; ++t) {
      unsigned int w = xw[t * 64 + lane];
      unsigned int lo = w & 0xffffu;
      float f = bf2f((unsigned short)lo);
      float af = fabsf(f);
      if (lo != 0u && (af > 1e4f || af < 1e-30f)) wild++;
    }
    #pragma unroll
    for (int m = 1; m < 64; m <<= 1) wild += __shfl_xor(wild, m);
    int zeros = 0;
    for (int t = 0; t < 2; ++t) {
      if (ei[(t * 64 + lane) * 2 + 1] == 0) zeros++;
    }
    #pragma unroll
    for (int m = 1; m < 64; m <<= 1) zeros += __shfl_xor(zeros, m);
    if (lane == 0) {
      flags[0] = (wild > 100) ? 1 : 0;   // 1: floats f32
      flags[1] = (zeros > 100) ? 1 : 0;  // 1: indices int64
    }
  }
}

__global__ void k_count(const int* __restrict__ ei, int* __restrict__ counts,
                        const int* __restrict__ flags) {
  int i64 = flags[1];
  int i = blockIdx.x * blockDim.x + threadIdx.x;
  if (i < EE) {
    int d = i64 ? ei[2 * (EE + i)] : ei[EE + i];
    atomicAdd(&counts[d], 1);
  }
}

__global__ __launch_bounds__(256) void k_scan1(const int* __restrict__ counts,
                                               int* __restrict__ tmpoff,
                                               int* __restrict__ bsum) {
  __shared__ int s[256];
  int t = threadIdx.x;
  int i = blockIdx.x * 256 + t;
  int v = (i < NN) ? counts[i] : 0;
  s[t] = v;
  __syncthreads();
  for (int off = 1; off < 256; off <<= 1) {
    int x = (t >= off) ? s[t - off] : 0;
    __syncthreads();
    s[t] += x;
    __syncthreads();
  }
  if (i < NN) tmpoff[i] = s[t] - v;
  if (t == 255) bsum[blockIdx.x] = s[255];
}

// per block: base = sum(bsum[0..blockIdx-1]); offsets = tmpoff + base
__global__ __launch_bounds__(256) void k_scan3(const int* __restrict__ tmpoff,
                                               const int* __restrict__ bsum,
                                               int* __restrict__ offsets,
                                               int* __restrict__ cursor) {
  __shared__ int sbase;
  if (threadIdx.x < 64) {
    int t = threadIdx.x;
    int v = (t < SCANB && t < (int)blockIdx.x) ? bsum[t] : 0;
    #pragma unroll
    for (int msk = 1; msk < 64; msk <<= 1) v += __shfl_xor(v, msk);
    if (t == 0) sbase = v;
  }
  __syncthreads();
  int base = sbase;
  int i = blockIdx.x * 256 + (int)threadIdx.x;
  if (i < NN) {
    int o = tmpoff[i] + base;
    offsets[i] = o;
    cursor[i] = o;
  }
  if (i == 0) offsets[NN] = EE;
}

__global__ void k_fill_sort(const int* __restrict__ ei, const void* __restrict__ ew,
                            int* __restrict__ cursor, int2* __restrict__ eS,
                            const int* __restrict__ flags) {
  int isf = flags[0];
  int i64 = flags[1];
  int i = blockIdx.x * blockDim.x + threadIdx.x;
  if (i < EE) {
    int s, d;
    if (i64) { s = ei[2 * i]; d = ei[2 * (EE + i)]; }
    else     { s = ei[i];     d = ei[EE + i]; }
    float wv = isf ? ((const float*)ew)[i] : bf2f(((const unsigned short*)ew)[i]);
    int p = atomicAdd(&cursor[d], 1);
    eS[p] = make_int2(s, __float_as_int(wv));
  }
}

struct PackArgs {
  const void* W[8];    // 256x256 weight matrices
  const void* B8[8];   // 256 biases
  const void* WeWb[4]; // we1(256), wb1(768), we2(256), wb2(768)
  const void* x;
};

// fused param pack. blocks 0..127: W transpose via 64x64 LDS tiles (coalesced both ways).
// blocks 128..143: biases + We/Wb. blocks 144+: x -> Ah fp16 (zero-pad rows >= NN).
__global__ __launch_bounds__(256) void k_pack(PackArgs pa, _Float16* __restrict__ Bh,
                                              float* __restrict__ bvec,
                                              float* __restrict__ WeWbF,
                                              _Float16* __restrict__ Ah,
                                              const int* __restrict__ flags) {
  __shared__ _Float16 lds[64][66];
  int isf = flags[0];
  int bid = (int)blockIdx.x, tid = (int)threadIdx.x;
  if (bid < 128) {
    int m = bid >> 4, t = bid & 15, tr = t >> 2, tc = t & 3;
    const void* Wm = pa.W[m];
    #pragma unroll
    for (int rep = 0; rep < 16; ++rep) {
      int idx = rep * 256 + tid;
      int r = idx >> 6, c = idx & 63;
      lds[r][c] = (_Float16)ldf(Wm, (tr * 64 + r) * 256 + tc * 64 + c, isf);
    }
    __syncthreads();
    _Float16* out = Bh + (size_t)m * 65536;
    #pragma unroll
    for (int rep = 0; rep < 16; ++rep) {
      int idx = rep * 256 + tid;
      int r = idx >> 6, c = idx & 63;
      out[(tc * 64 + r) * 256 + tr * 64 + c] = lds[c][r];
    }
    return;
  }
  int b2 = bid - 128;
  if (b2 < 16) {
    int i = b2 * 256 + tid;  // 0..4095
    if (i < 2048) {
      bvec[i] = ldf(pa.B8[i >> 8], i & 255, isf);
    } else {
      i -= 2048;
      int which, k;
      if (i < 256)       { which = 0; k = i; }
      else if (i < 1024) { which = 1; k = i - 256; }
      else if (i < 1280) { which = 2; k = i - 1024; }
      else               { which = 3; k = i - 1280; }
      WeWbF[i] = ldf(pa.WeWb[which], k, isf);
    }
    return;
  }
  int i = (b2 - 16) * 256 + tid;
  if (i < NROWS * 64) {
    f16x4 h;
    if (i >= NN * 64) {
      h = (f16x4)(_Float16)0.f;
    } else {
      float v[4];
      if (isf) {
        float4 t = reinterpret_cast<const float4*>(pa.x)[i];
        v[0] = t.x; v[1] = t.y; v[2] = t.z; v[3] = t.w;
      } else {
        ushort4 t = reinterpret_cast<const ushort4*>(pa.x)[i];
        v[0] = bf2f(t.x); v[1] = bf2f(t.y); v[2] = bf2f(t.z); v[3] = bf2f(t.w);
      }
      #pragma unroll
      for (int j = 0; j < 4; ++j) h[j] = (_Float16)v[j];
    }
    reinterpret_cast<f16x4*>(Ah)[i] = h;
  }
}

// fp16 MFMA GEMM, 32-row x 256-col tiles, single pass for all matrices.
// blockIdx.y = matrix: 0=Q(fp16) 1=K(fp16) 2=V(fp16) 3=XR(f32)
__global__ __launch_bounds__(256, 4) void k_gemm_mfma(
    const _Float16* __restrict__ Ah, const _Float16* __restrict__ Bh,
    const float* __restrict__ bvec, _Float16* __restrict__ Qh,
    _Float16* __restrict__ KVh, float* __restrict__ XRf) {
  int tid = (int)threadIdx.x;
  int wave = tid >> 6, lane = tid & 63;
  int lr = lane & 15;
  int kg = (lane >> 4) << 3;
  int mat = blockIdx.y;
  int rowBase = blockIdx.x << 5;
  int colBase = (mat << 8) + (wave << 6);
  const _Float16* a0 = Ah + (size_t)(rowBase + lr) * 256 + kg;
  const _Float16* b0 = Bh + (size_t)(colBase + lr) * 256 + kg;
  f32x4 acc[2][4] = {};
  #pragma unroll
  for (int ks = 0; ks < 256; ks += 32) {
    f16x8 ah0 = *reinterpret_cast<const f16x8*>(a0 + ks);
    f16x8 ah1 = *reinterpret_cast<const f16x8*>(a0 + 16 * 256 + ks);
    f16x8 bh[4];
    #pragma unroll
    for (int cf = 0; cf < 4; ++cf)
      bh[cf] = *reinterpret_cast<const f16x8*>(b0 + cf * 16 * 256 + ks);
    #pragma unroll
    for (int cf = 0; cf < 4; ++cf) {
      acc[0][cf] = __builtin_amdgcn_mfma_f32_16x16x32_f16(ah0, bh[cf], acc[0][cf], 0, 0, 0);
      acc[1][cf] = __builtin_amdgcn_mfma_f32_16x16x32_f16(ah1, bh[cf], acc[1][cf], 0, 0, 0);
    }
  }
  int rj = (lane >> 4) << 2;
  int colLoc = (wave << 6);
  #pragma unroll
  for (int rf = 0; rf < 2; ++rf) {
    #pragma unroll
    for (int cf = 0; cf < 4; ++cf) {
      int col = colLoc + cf * 16 + lr;
      float bb = bvec[(mat << 8) + col];
      #pragma unroll
      for (int j = 0; j < 4; ++j) {
        int row = rowBase + rf * 16 + rj + j;
        if (row < NN) {
          float val = acc[rf][cf][j] + bb;
          if (mat == 0)      Qh[(size_t)row * DIM + col] = (_Float16)val;
          else if (mat == 3) XRf[(size_t)row * DIM + col] = val;
          else KVh[(size_t)row * 512 + ((mat == 2) ? 256 : 0) + col] = (_Float16)val;
        }
      }
    }
  }
}

// single-edge online-softmax step (qwe/sw form)
#define ATT_STEP(KK, VV, WW) do { \
    f16x2 kka = {KK[0], KK[1]}, kkb = {KK[2], KK[3]}; \
    float pt = FDOT2(kka, qha, FDOT2(kkb, qhb, 0.f)); \
    pt += __shfl_xor(pt, 1); \
    pt += __shfl_xor(pt, 2); \
    pt += __shfl_xor(pt, 4); \
    float alpha = fmaf(WW, qwe, pt) * 0.17677669529663687f; \
    float nm = fmaxf(m, alpha); \
    float sc = __expf(m - nm); \
    float pe = __expf(alpha - nm); \
    l = fmaf(l, sc, pe); \
    sw = fmaf(sw, sc, pe * WW); \
    a0 = fmaf(a0, sc, pe * (float)VV[0]); \
    a1 = fmaf(a1, sc, pe * (float)VV[1]); \
    a2 = fmaf(a2, sc, pe * (float)VV[2]); \
    a3 = fmaf(a3, sc, pe * (float)VV[3]); \
    m = nm; \
  } while (0)

// two edges per update: independent packed dots, one max3, one rescale
#define PAIR_STEP(K0, V0, W0, K1, V1, W1) do { \
    f16x2 k0a = {K0[0], K0[1]}, k0b = {K0[2], K0[3]}; \
    f16x2 k1a = {K1[0], K1[1]}, k1b = {K1[2], K1[3]}; \
    float pt0 = FDOT2(k0a, qha, FDOT2(k0b, qhb, 0.f)); \
    float pt1 = FDOT2(k1a, qha, FDOT2(k1b, qhb, 0.f)); \
    pt0 += __shfl_xor(pt0, 1); pt1 += __shfl_xor(pt1, 1); \
    pt0 += __shfl_xor(pt0, 2); pt1 += __shfl_xor(pt1, 2); \
    pt0 += __shfl_xor(pt0, 4); pt1 += __shfl_xor(pt1, 4); \
    float al0 = fmaf(W0, qwe, pt0) * 0.17677669529663687f; \
    float al1 = fmaf(W1, qwe, pt1) * 0.17677669529663687f; \
    float nm = fmaxf(fmaxf(m, al0), al1); \
    float sc = __expf(m - nm); \
    float p0 = __expf(al0 - nm); \
    float p1 = __expf(al1 - nm); \
    l = fmaf(l, sc, p0 + p1); \
    sw = fmaf(sw, sc, fmaf(p0, W0, p1 * W1)); \
    a0 = fmaf(a0, sc, fmaf(p0, (float)V0[0], p1 * (float)V1[0])); \
    a1 = fmaf(a1, sc, fmaf(p0, (float)V0[1], p1 * (float)V1[1])); \
    a2 = fmaf(a2, sc, fmaf(p0, (float)V0[2], p1 * (float)V1[2])); \
    a3 = fmaf(a3, sc, fmaf(p0, (float)V0[3], p1 * (float)V1[3])); \
    m = nm; \
  } while (0)

// one wave per node; pair-batched online softmax with algebraic We elimination.
__global__ __launch_bounds__(256) void k_attn(
    const _Float16* __restrict__ Qh, const _Float16* __restrict__ KVh,
    const float* __restrict__ XRf, const float* __restrict__ We,
    const float* __restrict__ Wb, const int2* __restrict__ eS,
    const int* __restrict__ offsets, _Float16* __restrict__ Ah,
    float* __restrict__ FinalOut) {
  int wid = (int)threadIdx.x >> 6, lane = (int)threadIdx.x & 63;
  int node = blockIdx.x * 4 + wid;
  if (node >= NN) return;
  int d0 = lane * 4;
  const f16x4 qh4 = *reinterpret_cast<const f16x4*>(&Qh[(size_t)node * DIM + d0]);
  const float4 x4 = *reinterpret_cast<const float4*>(&XRf[(size_t)node * DIM + d0]);
  const float4 we4 = *reinterpret_cast<const float4*>(&We[d0]);
  const float4 wo = *reinterpret_cast<const float4*>(&Wb[d0]);
  const float4 wx = *reinterpret_cast<const float4*>(&Wb[DIM + d0]);
  const float4 wd = *reinterpret_cast<const float4*>(&Wb[2 * DIM + d0]);
  f16x2 qha = {qh4[0], qh4[1]};
  f16x2 qhb = {qh4[2], qh4[3]};
  float qwe = (float)qh4[0] * we4.x + (float)qh4[1] * we4.y
            + (float)qh4[2] * we4.z + (float)qh4[3] * we4.w;
  qwe += __shfl_xor(qwe, 1);
  qwe += __shfl_xor(qwe, 2);
  qwe += __shfl_xor(qwe, 4);
  int beg = offsets[node], end = offsets[node + 1];
  beg = __builtin_amdgcn_readfirstlane(beg);
  end = __builtin_amdgcn_readfirstlane(end);
  float m = -INFINITY, l = 0.f, sw = 0.f, a0 = 0.f, a1 = 0.f, a2 = 0.f, a3 = 0.f;
  int p = beg;
  if ((end - beg) & 1) {
    int2 e = eS[p];
    float w0 = __int_as_float(e.y);
    const _Float16* r = KVh + (size_t)e.x * 512 + d0;
    f16x4 k0 = *reinterpret_cast<const f16x4*>(r);
    f16x4 v0 = *reinterpret_cast<const f16x4*>(r + 256);
    ATT_STEP(k0, v0, w0);
    ++p;
  }
  if (p < end) {  // even remaining count >= 2
    int2 eA0 = eS[p], eA1 = eS[p + 1];
    int pb = (p + 3 < end) ? (p + 2) : p;
    int2 eB0 = eS[pb], eB1 = eS[pb + 1];
    const _Float16* rA0 = KVh + (size_t)eA0.x * 512 + d0;
    const _Float16* rA1 = KVh + (size_t)eA1.x * 512 + d0;
    const _Float16* rB0 = KVh + (size_t)eB0.x * 512 + d0;
    const _Float16* rB1 = KVh + (size_t)eB1.x * 512 + d0;
    f16x4 kA0 = *reinterpret_cast<const f16x4*>(rA0), vA0 = *reinterpret_cast<const f16x4*>(rA0 + 256);
    f16x4 kA1 = *reinterpret_cast<const f16x4*>(rA1), vA1 = *reinterpret_cast<const f16x4*>(rA1 + 256);
    f16x4 kB0 = *reinterpret_cast<const f16x4*>(rB0), vB0 = *reinterpret_cast<const f16x4*>(rB0 + 256);
    f16x4 kB1 = *reinterpret_cast<const f16x4*>(rB1), vB1 = *reinterpret_cast<const f16x4*>(rB1 + 256);
    float wA0 = __int_as_float(eA0.y), wA1 = __int_as_float(eA1.y);
    float wB0 = __int_as_float(eB0.y), wB1 = __int_as_float(eB1.y);
    #pragma unroll 2
    for (; p + 2 < end; p += 2) {
      int pc = (p + 5 < end) ? (p + 4) : p;
      int2 eC0 = eS[pc], eC1 = eS[pc + 1];
      const _Float16* rC0 = KVh + (size_t)eC0.x * 512 + d0;
      const _Float16* rC1 = KVh + (size_t)eC1.x * 512 + d0;
      f16x4 kC0 = *reinterpret_cast<const f16x4*>(rC0), vC0 = *reinterpret_cast<const f16x4*>(rC0 + 256);
      f16x4 kC1 = *reinterpret_cast<const f16x4*>(rC1), vC1 = *reinterpret_cast<const f16x4*>(rC1 + 256);
      float wC0 = __int_as_float(eC0.y), wC1 = __int_as_float(eC1.y);
      PAIR_STEP(kA0, vA0, wA0, kA1, vA1, wA1);
      kA0 = kB0; vA0 = vB0; wA0 = wB0; kA1 = kB1; vA1 = vB1; wA1 = wB1;
      kB0 = kC0; vB0 = vC0; wB0 = wC0; kB1 = kC1; vB1 = vC1; wB1 = wC1;
    }
    PAIR_STEP(kA0, vA0, wA0, kA1, vA1, wA1);
  }
  float inv = 1.f / (l + 1e-16f);
  float o0 = fmaf(sw, we4.x, a0) * inv;
  float o1 = fmaf(sw, we4.y, a1) * inv;
  float o2 = fmaf(sw, we4.z, a2) * inv;
  float o3 = fmaf(sw, we4.w, a3) * inv;
  float part = o0 * wo.x + o1 * wo.y + o2 * wo.z + o3 * wo.w
             + x4.x * wx.x + x4.y * wx.y + x4.z * wx.z + x4.w * wx.w
             + (o0 - x4.x) * wd.x + (o1 - x4.y) * wd.y
             + (o2 - x4.z) * wd.z + (o3 - x4.w) * wd.w;
  #pragma unroll
  for (int msk = 1; msk < 64; msk <<= 1) part += __shfl_xor(part, msk);
  float beta = 1.f / (1.f + __expf(-part));
  float h0 = beta * x4.x + (1.f - beta) * o0;
  float h1 = beta * x4.y + (1.f - beta) * o1;
  float h2 = beta * x4.z + (1.f - beta) * o2;
  float h3 = beta * x4.w + (1.f - beta) * o3;
  if (FinalOut) {
    float4 h; h.x = h0; h.y = h1; h.z = h2; h.w = h3;
    *reinterpret_cast<float4*>(&FinalOut[(size_t)node * DIM + d0]) = h;
  } else {
    f16x4 hh;
    hh[0] = (_Float16)h0; hh[1] = (_Float16)h1;
    hh[2] = (_Float16)h2; hh[3] = (_Float16)h3;
    *reinterpret_cast<f16x4*>(&Ah[(size_t)node * DIM + d0]) = hh;
  }
}

static inline size_t align256(size_t v) { return (v + 255) & ~(size_t)255; }

extern "C" void kernel_launch(void* const* d_in, const int* in_sizes, int n_in,
                              void* d_out, int out_size, void* d_ws, size_t ws_size,
                              hipStream_t stream) {
  const void* x = d_in[0];
  const int* eidx = (const int*)d_in[1];
  const void* ew = d_in[2];

  char* w = (char*)d_ws;
  size_t pos = 0;
  int* flags = (int*)(w + pos); pos = align256(pos + 2 * sizeof(int));
  _Float16* Qh = (_Float16*)(w + pos); pos = align256(pos + (size_t)NROWS * DIM * 2);
  float* XRf = (float*)(w + pos); pos = align256(pos + (size_t)NROWS * DIM * 4);
  _Float16* KVh = (_Float16*)(w + pos); pos = align256(pos + (size_t)NROWS * 512 * 2);
  _Float16* Ah = (_Float16*)(w + pos); pos = align256(pos + (size_t)NROWS * DIM * 2);
  _Float16* Bh = (_Float16*)(w + pos); pos = align256(pos + (size_t)8 * 65536 * 2);
  float* bvec  = (float*)(w + pos); pos = align256(pos + 2048 * 4);
  float* WeWbF = (float*)(w + pos); pos = align256(pos + 2048 * 4);
  int2* eS   = (int2*)(w + pos);   pos = align256(pos + (size_t)EE * 8);
  int* counts  = (int*)(w + pos);  pos = align256(pos + (size_t)NN * 4);
  int* offsets = (int*)(w + pos);  pos = align256(pos + (size_t)(NN + 1) * 4);
  int* cursor  = (int*)(w + pos);  pos = align256(pos + (size_t)NN * 4);
  int* tmpoff  = (int*)(w + pos);  pos = align256(pos + (size_t)NN * 4);
  int* bsum    = (int*)(w + pos);  pos = align256(pos + 64 * 4);

  // params: d_in[3..22], order per group: Wq bq Wk bk Wv bv We Wskip bskip Wbeta
  PackArgs pa;
  pa.x = x;
  for (int g = 0; g < 2; ++g) {
    const void* const* pp = &d_in[3 + g * 10];
    pa.W[g * 4 + 0] = pp[0]; pa.W[g * 4 + 1] = pp[2];
    pa.W[g * 4 + 2] = pp[4]; pa.W[g * 4 + 3] = pp[7];
    pa.B8[g * 4 + 0] = pp[1]; pa.B8[g * 4 + 1] = pp[3];
    pa.B8[g * 4 + 2] = pp[5]; pa.B8[g * 4 + 3] = pp[8];
    pa.WeWb[g * 2 + 0] = pp[6];
    pa.WeWb[g * 2 + 1] = pp[9];
  }

  k_detect_zero<<<SCANB, 256, 0, stream>>>((const unsigned int*)x, eidx, flags, counts);
  k_pack<<<128 + 16 + (NROWS * 64 + 255) / 256, 256, 0, stream>>>(
      pa, Bh, bvec, WeWbF, Ah, flags);
  k_count<<<(EE + 255) / 256, 256, 0, stream>>>(eidx, counts, flags);
  k_scan1<<<SCANB, 256, 0, stream>>>(counts, tmpoff, bsum);
  k_scan3<<<SCANB, 256, 0, stream>>>(tmpoff, bsum, offsets, cursor);
  k_fill_sort<<<(EE + 255) / 256, 256, 0, stream>>>(eidx, ew, cursor, eS, flags);

  for (int layer = 0; layer < 3; ++layer) {
    int g = (layer == 0) ? 0 : 1;
    k_gemm_mfma<<<dim3(NROWS / 32, 4), 256, 0, stream>>>(
        Ah, Bh + (size_t)g * 4 * 65536, bvec + g * 1024, Qh, KVh, XRf);
    k_attn<<<(NN + 3) / 4, 256, 0, stream>>>(Qh, KVh, XRf,
        WeWbF + (g ? 1024 : 0), WeWbF + (g ? 1280 : 256),
        eS, offsets, Ah, (layer == 2) ? (float*)d_out : nullptr);
  }
}